// Round 1
// baseline (1281.051 us; speedup 1.0000x reference)
//
#include <hip/hip_runtime.h>

#define C_    256
#define DHW   110592
#define NTOK  221184   // B * DHW
#define NSEQ  216      // tokens per window
#define NPAD  224
#define NH    8
#define DH    32

typedef _Float16 half8  __attribute__((ext_vector_type(8)));
typedef _Float16 half4v __attribute__((ext_vector_type(4)));
typedef float    float4v __attribute__((ext_vector_type(4)));

// ---------------- Kernel 0: convert proj_w fp32 -> fp16 ----------------
__global__ __launch_bounds__(256) void k_convert_w(const float* __restrict__ w,
                                                   _Float16* __restrict__ wh) {
    int i = blockIdx.x * 256 + threadIdx.x;
#pragma unroll
    for (int j = 0; j < 4; ++j) {
        int idx = i + j * 16384;
        wh[idx] = (_Float16)w[idx];
    }
}

// ---------------- Kernel 1: window-partition + LayerNorm (q,k,v) ----------------
// Block: 64 consecutive flat tokens of one batch. 256 threads = 4 channel-groups x 64 tokens.
__global__ __launch_bounds__(256) void k_ln(
    const float* __restrict__ q_map, const float* __restrict__ k_map,
    const float* __restrict__ v_map,
    const float* __restrict__ lnq_w, const float* __restrict__ lnq_b,
    const float* __restrict__ lnkv_w, const float* __restrict__ lnkv_b,
    _Float16* __restrict__ qo, _Float16* __restrict__ ko, _Float16* __restrict__ vo)
{
    __shared__ float ps1[4][64];
    __shared__ float ps2[4][64];
    const int tid = threadIdx.x;
    const int g = tid >> 6, t = tid & 63;
    const int blk = blockIdx.x;
    const int b = blk / 1728;
    const int pos = (blk - b * 1728) * 64 + t;

    // token -> (window, n) output row
    const int d = pos / 2304, rem = pos % 2304, h = rem / 48, w = rem % 48;
    const int wi = (d / 6) * 64 + (h / 6) * 8 + (w / 6);
    const int n = (d % 6) * 36 + (h % 6) * 6 + (w % 6);
    const long outRow = (long)(b * 512 + wi) * NSEQ + n;

    const float* xin[3] = {q_map, k_map, v_map};
    _Float16* xout[3] = {qo, ko, vo};

    for (int m = 0; m < 3; ++m) {
        const float* xp = xin[m] + (size_t)b * C_ * DHW + pos;
        float s1 = 0.f, s2 = 0.f;
#pragma unroll 8
        for (int i = 0; i < 64; ++i) {
            int c = (g << 6) + i;
            float x = xp[(size_t)c * DHW];
            s1 += x; s2 += x * x;
        }
        ps1[g][t] = s1; ps2[g][t] = s2;
        __syncthreads();
        float mu  = (ps1[0][t] + ps1[1][t] + ps1[2][t] + ps1[3][t]) * (1.f / 256.f);
        float ex2 = (ps2[0][t] + ps2[1][t] + ps2[2][t] + ps2[3][t]) * (1.f / 256.f);
        float rstd = rsqrtf(ex2 - mu * mu + 1e-5f);
        const float* wv = (m == 0) ? lnq_w : lnkv_w;
        const float* bv = (m == 0) ? lnq_b : lnkv_b;
        _Float16* op = xout[m] + (size_t)outRow * C_;
#pragma unroll 4
        for (int i = 0; i < 16; ++i) {
            int c0 = (g << 6) + i * 4;
            float4 wq = *(const float4*)(wv + c0);
            float4 bq = *(const float4*)(bv + c0);
            half4v y;
            y[0] = (_Float16)((xp[(size_t)(c0 + 0) * DHW] - mu) * rstd * wq.x + bq.x);
            y[1] = (_Float16)((xp[(size_t)(c0 + 1) * DHW] - mu) * rstd * wq.y + bq.y);
            y[2] = (_Float16)((xp[(size_t)(c0 + 2) * DHW] - mu) * rstd * wq.z + bq.z);
            y[3] = (_Float16)((xp[(size_t)(c0 + 3) * DHW] - mu) * rstd * wq.w + bq.w);
            *(half4v*)(op + c0) = y;
        }
        __syncthreads();
    }
}

// ---------------- Kernel 2: per-(window, head) attention ----------------
// 4 waves; wave handles q-tiles {w, w+4, w+8, w+12} of 14 (NPAD=224).
// S^T = K * Q^T via mfma so the softmax row lives in lane groups (2 shfl_xor reduce).
__global__ __launch_bounds__(256) void k_attn(
    const _Float16* __restrict__ qh, const _Float16* __restrict__ kh,
    const _Float16* __restrict__ vh, _Float16* __restrict__ ao)
{
    __shared__ _Float16 Ks[NPAD * 40];     // K [224][32], stride 40
    __shared__ _Float16 Vt[DH * 232];      // V^T [32][224], stride 232
    __shared__ _Float16 Ps[4 * 16 * 232];  // per-wave P [16][224], stride 232

    const int tid = threadIdx.x;
    const int wave = tid >> 6, lane = tid & 63;
    const int q16 = lane & 15, g = lane >> 4;
    const int win = blockIdx.x >> 3, head = blockIdx.x & 7;
    const size_t base = ((size_t)win * NSEQ) * C_ + head * DH;
    const _Float16* kg = kh + base;
    const _Float16* vg = vh + base;
    const _Float16* qg = qh + base;

    // stage K (zero-fill pad rows)
    for (int idx = tid; idx < NPAD * 8; idx += 256) {
        int r = idx >> 3, cq = idx & 7;
        half4v val{};
        if (r < NSEQ) val = *(const half4v*)(kg + (size_t)r * C_ + cq * 4);
        *(half4v*)(&Ks[r * 40 + cq * 4]) = val;
    }
    // stage V transposed (zero-fill pad cols)
    for (int idx = tid; idx < NPAD * DH; idx += 256) {
        int dd = idx & 31, r = idx >> 5;
        _Float16 v = (_Float16)0;
        if (r < NSEQ) v = vg[(size_t)r * C_ + dd];
        Vt[dd * 232 + r] = v;
    }
    __syncthreads();

    constexpr float SC = 0.17677669529663687f * 1.4426950408889634f; // scale * log2(e)
    _Float16* Pw = &Ps[wave * 16 * 232];

    for (int qt = wave; qt < 14; qt += 4) {
        const int qtok = qt * 16 + q16;
        half8 bq{};
        if (qtok < NSEQ) bq = *(const half8*)(qg + (size_t)qtok * C_ + g * 8);

        float4v s[14];
#pragma unroll
        for (int kt = 0; kt < 14; ++kt) {
            half8 a = *(const half8*)(&Ks[(kt * 16 + q16) * 40 + g * 8]);
            float4v z{};
            s[kt] = __builtin_amdgcn_mfma_f32_16x16x32_f16(a, bq, z, 0, 0, 0);
        }
        float mx = -3e38f;
#pragma unroll
        for (int kt = 0; kt < 14; ++kt)
#pragma unroll
            for (int r = 0; r < 4; ++r) {
                if (kt * 16 + g * 4 + r >= NSEQ) s[kt][r] = -3e38f;
                mx = fmaxf(mx, s[kt][r]);
            }
        mx = fmaxf(mx, __shfl_xor(mx, 16));
        mx = fmaxf(mx, __shfl_xor(mx, 32));
        float sum = 0.f;
#pragma unroll
        for (int kt = 0; kt < 14; ++kt)
#pragma unroll
            for (int r = 0; r < 4; ++r) {
                float p = exp2f((s[kt][r] - mx) * SC);
                s[kt][r] = p;
                sum += p;
            }
        sum += __shfl_xor(sum, 16);
        sum += __shfl_xor(sum, 32);
        float rinv = 1.f / sum;

        // store P [q][k] (unnormalized)
#pragma unroll
        for (int kt = 0; kt < 14; ++kt) {
            half4v hp;
            hp[0] = (_Float16)s[kt][0]; hp[1] = (_Float16)s[kt][1];
            hp[2] = (_Float16)s[kt][2]; hp[3] = (_Float16)s[kt][3];
            *(half4v*)(&Pw[q16 * 232 + kt * 16 + g * 4]) = hp;
        }

        // PV: out[16q][32d]
#pragma unroll
        for (int dt = 0; dt < 2; ++dt) {
            float4v o{};
#pragma unroll
            for (int kc = 0; kc < 7; ++kc) {
                half8 pa = *(const half8*)(&Pw[q16 * 232 + kc * 32 + g * 8]);
                half8 vb = *(const half8*)(&Vt[(dt * 16 + q16) * 232 + kc * 32 + g * 8]);
                o = __builtin_amdgcn_mfma_f32_16x16x32_f16(pa, vb, o, 0, 0, 0);
            }
#pragma unroll
            for (int r = 0; r < 4; ++r) {
                float rq = __shfl(rinv, g * 4 + r);
                int qr = qt * 16 + g * 4 + r;
                if (qr < NSEQ)
                    ao[((size_t)win * NSEQ + qr) * C_ + head * DH + dt * 16 + q16] =
                        (_Float16)(o[r] * rq);
            }
        }
    }
}

// ---------------- Kernel 3: projection GEMM + bias + window reverse ----------------
__global__ __launch_bounds__(256) void k_proj(
    const _Float16* __restrict__ ah, const _Float16* __restrict__ wh,
    const float* __restrict__ pb, float* __restrict__ out)
{
    __shared__ _Float16 As[64 * 264]; // 64 token rows x 256 (stride 264)
    const int tid = threadIdx.x;
    const int wave = tid >> 6, lane = tid & 63;
    const int c16 = lane & 15, g = lane >> 4;
    const size_t mbase = (size_t)blockIdx.x * 64;

    for (int idx = tid; idx < 64 * 64; idx += 256) {
        int row = idx >> 6, cc = (idx & 63) * 4;
        half4v v = *(const half4v*)(ah + mbase * C_ + (size_t)idx * 4);
        *(half4v*)(&As[row * 264 + cc]) = v;
    }
    __syncthreads();

    const int row0 = wave * 16;
    half8 afr[8];
#pragma unroll
    for (int kc = 0; kc < 8; ++kc)
        afr[kc] = *(const half8*)(&As[(row0 + c16) * 264 + kc * 32 + g * 8]);

    // window-reverse addresses for this lane's 4 output rows
    size_t obase[4];
#pragma unroll
    for (int r = 0; r < 4; ++r) {
        int tok = (int)mbase + row0 + g * 4 + r;
        int win = tok / NSEQ, n = tok - win * NSEQ;
        int b = win >> 9, wi = win & 511;
        int dd = n / 36, rr = n - dd * 36, hh = rr / 6, ww = rr - hh * 6;
        int d = (wi >> 6) * 6 + dd;
        int h = ((wi >> 3) & 7) * 6 + hh;
        int w = (wi & 7) * 6 + ww;
        obase[r] = (size_t)b * C_ * DHW + (size_t)(d * 2304 + h * 48 + w);
    }

#pragma unroll 4
    for (int ct = 0; ct < 16; ++ct) {
        int c = ct * 16 + c16;
        float bias = pb[c];
        float4v o = {bias, bias, bias, bias};
#pragma unroll
        for (int kc = 0; kc < 8; ++kc) {
            half8 bf = *(const half8*)(wh + (size_t)c * C_ + kc * 32 + g * 8);
            o = __builtin_amdgcn_mfma_f32_16x16x32_f16(afr[kc], bf, o, 0, 0, 0);
        }
#pragma unroll
        for (int r = 0; r < 4; ++r)
            out[obase[r] + (size_t)c * DHW] = o[r];
    }
}

extern "C" void kernel_launch(void* const* d_in, const int* in_sizes, int n_in,
                              void* d_out, int out_size, void* d_ws, size_t ws_size,
                              hipStream_t stream)
{
    const float* q_map  = (const float*)d_in[0];
    const float* k_map  = (const float*)d_in[1];
    const float* v_map  = (const float*)d_in[2];
    const float* lnq_w  = (const float*)d_in[3];
    const float* lnq_b  = (const float*)d_in[4];
    const float* lnkv_w = (const float*)d_in[5];
    const float* lnkv_b = (const float*)d_in[6];
    const float* proj_w = (const float*)d_in[7];
    const float* proj_b = (const float*)d_in[8];
    float* out = (float*)d_out;

    const size_t SZ = (size_t)NTOK * C_; // elements per fp16 matrix
    _Float16* qh = (_Float16*)d_ws;
    _Float16* kh = qh + SZ;
    _Float16* vh = kh + SZ;
    _Float16* ah = vh + SZ;
    _Float16* wh = ah + SZ;

    k_convert_w<<<64, 256, 0, stream>>>(proj_w, wh);
    k_ln<<<3456, 256, 0, stream>>>(q_map, k_map, v_map,
                                   lnq_w, lnq_b, lnkv_w, lnkv_b, qh, kh, vh);
    k_attn<<<8192, 256, 0, stream>>>(qh, kh, vh, ah);
    k_proj<<<3456, 256, 0, stream>>>(ah, wh, proj_b, out);
}

// Round 3
// 651.743 us; speedup vs baseline: 1.9656x; 1.9656x over previous
//
#include <hip/hip_runtime.h>

#define C_    256
#define DHW   110592
#define NTOK  221184   // B * DHW
#define NSEQ  216      // tokens per window
#define NH    8
#define DH    32

typedef _Float16 half8  __attribute__((ext_vector_type(8)));
typedef _Float16 half4v __attribute__((ext_vector_type(4)));
typedef __fp16   fp16x2 __attribute__((ext_vector_type(2)));
typedef float    float4v __attribute__((ext_vector_type(4)));

union H8U4 { half8 h; uint4 u; };
union H2U1 { fp16x2 h; unsigned u; };

static __device__ __forceinline__ unsigned pkrtz(float a, float b) {
    H2U1 t; t.h = __builtin_amdgcn_cvt_pkrtz(a, b); return t.u;
}

// ---------------- Kernel 0: convert proj_w fp32 -> fp16 ----------------
__global__ __launch_bounds__(256) void k_convert_w(const float* __restrict__ w,
                                                   _Float16* __restrict__ wh) {
    int i = blockIdx.x * 256 + threadIdx.x;
#pragma unroll
    for (int j = 0; j < 4; ++j) {
        int idx = i + j * 16384;
        wh[idx] = (_Float16)w[idx];
    }
}

// ---------------- Kernel 1: window-partition + LayerNorm, single-pass ----------------
// Block: 32 consecutive flat tokens of one matrix (grid.y selects q/k/v).
// 256 threads = 8 channel-groups x 32 tokens; x kept in registers.
__global__ __launch_bounds__(256) void k_ln(
    const float* __restrict__ q_map, const float* __restrict__ k_map,
    const float* __restrict__ v_map,
    const float* __restrict__ lnq_w, const float* __restrict__ lnq_b,
    const float* __restrict__ lnkv_w, const float* __restrict__ lnkv_b,
    _Float16* __restrict__ qo, _Float16* __restrict__ ko, _Float16* __restrict__ vo)
{
    __shared__ float ps1[8][32];
    __shared__ float ps2[8][32];
    const int tid = threadIdx.x;
    const int g = tid >> 5, t = tid & 31;
    const int m = blockIdx.y;
    const float* xm = (m == 0) ? q_map : (m == 1) ? k_map : v_map;
    _Float16*   xo = (m == 0) ? qo    : (m == 1) ? ko    : vo;
    const float* wv = (m == 0) ? lnq_w : lnkv_w;
    const float* bv = (m == 0) ? lnq_b : lnkv_b;

    const int blk = blockIdx.x;
    const int b = blk / 3456;
    const int pos = (blk - b * 3456) * 32 + t;

    const int d = pos / 2304, rem = pos % 2304, h = rem / 48, w = rem % 48;
    const int wi = (d / 6) * 64 + (h / 6) * 8 + (w / 6);
    const int n = (d % 6) * 36 + (h % 6) * 6 + (w % 6);
    const long outRow = (long)(b * 512 + wi) * NSEQ + n;

    const float* xp = xm + (size_t)b * C_ * DHW + pos;
    float x[32];
    float s1 = 0.f, s2 = 0.f;
#pragma unroll
    for (int i = 0; i < 32; ++i) {
        x[i] = xp[(size_t)(g * 32 + i) * DHW];
        s1 += x[i]; s2 += x[i] * x[i];
    }
    ps1[g][t] = s1; ps2[g][t] = s2;
    __syncthreads();
    float a1 = 0.f, a2 = 0.f;
#pragma unroll
    for (int gg = 0; gg < 8; ++gg) { a1 += ps1[gg][t]; a2 += ps2[gg][t]; }
    float mu = a1 * (1.f / 256.f);
    float rstd = rsqrtf(a2 * (1.f / 256.f) - mu * mu + 1e-5f);

    _Float16* op = xo + (size_t)outRow * C_ + g * 32;
#pragma unroll
    for (int i0 = 0; i0 < 32; i0 += 8) {
        half8 y;
#pragma unroll
        for (int i = 0; i < 8; ++i) {
            int c = g * 32 + i0 + i;
            y[i] = (_Float16)((x[i0 + i] - mu) * rstd * wv[c] + bv[c]);
        }
        *(half8*)(op + i0) = y;
    }
}

// ---------------- Kernel 2: per-(window, head) attention ----------------
// LDS: K [224][32] XOR-swizzled (16B cols), V blocked [k/8][32d][k&7]. No P buffer:
// P^T -> A-frag remap done in registers via cvt_pkrtz + shfl.
__global__ __launch_bounds__(256) void k_attn(
    const _Float16* __restrict__ qh, const _Float16* __restrict__ kh,
    const _Float16* __restrict__ vh, _Float16* __restrict__ ao)
{
    __shared__ _Float16 Ks[224 * 32];      // swizzled
    __shared__ _Float16 Vb[28 * 32 * 8];   // [kblk][d][k&7]

    const int tid = threadIdx.x;
    const int wave = tid >> 6, lane = tid & 63;
    const int q16 = lane & 15, g = lane >> 4;
    const int win = blockIdx.x >> 3, head = blockIdx.x & 7;
    const size_t base = ((size_t)win * NSEQ) * C_ + head * DH;
    const _Float16* kg = kh + base;
    const _Float16* vg = vh + base;
    const _Float16* qg = qh + base;

    // stage K (swizzled write), zero-fill pad rows
    for (int idx = tid; idx < 224 * 4; idx += 256) {
        int r = idx >> 2, c8 = idx & 3;
        half8 val{};
        if (r < NSEQ) val = *(const half8*)(kg + (size_t)r * C_ + c8 * 8);
        *(half8*)(&Ks[r * 32 + ((c8 ^ (r & 3)) * 8)]) = val;
    }
    // stage V blocked
    for (int idx = tid; idx < 224 * 4; idx += 256) {
        int r = idx >> 2, c8 = idx & 3;
        half8 val{};
        if (r < NSEQ) val = *(const half8*)(vg + (size_t)r * C_ + c8 * 8);
        _Float16* dst = &Vb[(r >> 3) * 256 + (r & 7)];
#pragma unroll
        for (int j = 0; j < 8; ++j) dst[(c8 * 8 + j) * 8] = val[j];
    }
    __syncthreads();

    constexpr float SC = 0.17677669529663687f * 1.4426950408889634f; // scale * log2(e)
    const int baseln = q16 + ((lane & 16) << 1);  // q16 + 32*(g&1)
    const int kswz = (g ^ (q16 & 3)) * 8;

    for (int qt = wave; qt < 14; qt += 4) {
        const int qtok = qt * 16 + q16;
        half8 bq{};
        if (qtok < NSEQ) bq = *(const half8*)(qg + (size_t)qtok * C_ + g * 8);

        float4v s[14];
#pragma unroll
        for (int kt = 0; kt < 14; ++kt) {
            half8 a = *(const half8*)(&Ks[(kt * 16 + q16) * 32 + kswz]);
            float4v z{};
            s[kt] = __builtin_amdgcn_mfma_f32_16x16x32_f16(a, bq, z, 0, 0, 0);
        }
        // row max (pads contribute 0 from zeroed K rows; 0-init is a valid bound)
        float mx = 0.f;
#pragma unroll
        for (int kt = 0; kt < 14; ++kt)
            mx = fmaxf(mx, fmaxf(fmaxf(s[kt][0], s[kt][1]), fmaxf(s[kt][2], s[kt][3])));
        mx = fmaxf(mx, __shfl_xor(mx, 16));
        mx = fmaxf(mx, __shfl_xor(mx, 32));
        const float mxs = mx * SC;
#pragma unroll
        for (int kt = 0; kt < 14; ++kt) {
#pragma unroll
            for (int r = 0; r < 4; ++r)
                s[kt][r] = exp2f(s[kt][r] * SC - mxs);
        }
        // zero pad k-tokens (rows 216..223 = kt13, g>=2)
        if (g >= 2) { s[13][0] = 0.f; s[13][1] = 0.f; s[13][2] = 0.f; s[13][3] = 0.f; }
        float sum0 = 0.f, sum1 = 0.f;
#pragma unroll
        for (int kt = 0; kt < 14; ++kt) { sum0 += s[kt][0] + s[kt][1]; sum1 += s[kt][2] + s[kt][3]; }
        float sum = sum0 + sum1;
        sum += __shfl_xor(sum, 16);
        sum += __shfl_xor(sum, 32);
        const float rinv = 1.f / sum;

        // PV with in-register P remap
        float4v o0{}, o1{};
#pragma unroll
        for (int c = 0; c < 7; ++c) {
            unsigned a0 = pkrtz(s[2 * c][0], s[2 * c][1]);
            unsigned a1 = pkrtz(s[2 * c][2], s[2 * c][3]);
            unsigned b0 = pkrtz(s[2 * c + 1][0], s[2 * c + 1][1]);
            unsigned b1 = pkrtz(s[2 * c + 1][2], s[2 * c + 1][3]);
            unsigned x0 = __shfl(a0, baseln),      x1 = __shfl(a1, baseln);
            unsigned x2 = __shfl(a0, baseln + 16), x3 = __shfl(a1, baseln + 16);
            unsigned y0 = __shfl(b0, baseln),      y1 = __shfl(b1, baseln);
            unsigned y2 = __shfl(b0, baseln + 16), y3 = __shfl(b1, baseln + 16);
            const bool hi = (g & 2);
            H8U4 pa;
            pa.u.x = hi ? y0 : x0;
            pa.u.y = hi ? y1 : x1;
            pa.u.z = hi ? y2 : x2;
            pa.u.w = hi ? y3 : x3;
            half8 vb0 = *(const half8*)(&Vb[(c * 4 + g) * 256 + q16 * 8]);
            half8 vb1 = *(const half8*)(&Vb[(c * 4 + g) * 256 + (16 + q16) * 8]);
            o0 = __builtin_amdgcn_mfma_f32_16x16x32_f16(pa.h, vb0, o0, 0, 0, 0);
            o1 = __builtin_amdgcn_mfma_f32_16x16x32_f16(pa.h, vb1, o1, 0, 0, 0);
        }
#pragma unroll
        for (int r = 0; r < 4; ++r) {
            float rq = __shfl(rinv, g * 4 + r);
            int qr = qt * 16 + g * 4 + r;
            if (qr < NSEQ) {
                size_t orow = ((size_t)win * NSEQ + qr) * C_ + head * DH;
                ao[orow + q16]      = (_Float16)(o0[r] * rq);
                ao[orow + 16 + q16] = (_Float16)(o1[r] * rq);
            }
        }
    }
}

// ---------------- Kernel 3: projection GEMM + bias + window reverse ----------------
// Block: 64 consecutive FLAT tokens; A rows gathered window-order; O^T tiles so
// stores are coalesced 64B segments. W read once per block (L2).
__global__ __launch_bounds__(256) void k_proj(
    const _Float16* __restrict__ ah, const _Float16* __restrict__ wh,
    const float* __restrict__ pb, float* __restrict__ out)
{
    __shared__ _Float16 As[64 * 264];
    const int tid = threadIdx.x;
    const int wave = tid >> 6, lane = tid & 63;
    const int l15 = lane & 15, g = lane >> 4;
    const long tok0 = (long)blockIdx.x * 64;

    {
        int r = tid >> 2, c8 = tid & 3;
        long tok = tok0 + r;
        int b = (int)(tok / DHW);
        int pos = (int)(tok - (long)b * DHW);
        int d = pos / 2304, rem = pos % 2304, hh = rem / 48, ww = rem % 48;
        int wi = (d / 6) * 64 + (hh / 6) * 8 + (ww / 6);
        int n = (d % 6) * 36 + (hh % 6) * 6 + (ww % 6);
        const _Float16* src = ah + ((size_t)(b * 512 + wi) * NSEQ + n) * C_;
        _Float16* dst = &As[r * 264];
#pragma unroll
        for (int i = 0; i < 8; ++i)
            *(half8*)(dst + c8 * 8 + i * 32) = *(const half8*)(src + c8 * 8 + i * 32);
    }
    __syncthreads();

    const int b0 = (int)(tok0 / DHW);
    const int pos0 = (int)(tok0 - (long)b0 * DHW);
    float* ob = out + (size_t)b0 * C_ * DHW + pos0;

#pragma unroll
    for (int ct = 0; ct < 4; ++ct) {
        const int c0 = wave * 64 + ct * 16;
        half8 afr[8];
#pragma unroll
        for (int kc = 0; kc < 8; ++kc)
            afr[kc] = *(const half8*)(wh + (size_t)(c0 + l15) * C_ + kc * 32 + g * 8);
        float4 bq = *(const float4*)(pb + c0 + g * 4);
#pragma unroll
        for (int tt = 0; tt < 4; ++tt) {
            float4v o = {bq.x, bq.y, bq.z, bq.w};
#pragma unroll
            for (int kc = 0; kc < 8; ++kc) {
                half8 bfr = *(const half8*)(&As[(tt * 16 + l15) * 264 + kc * 32 + g * 8]);
                o = __builtin_amdgcn_mfma_f32_16x16x32_f16(afr[kc], bfr, o, 0, 0, 0);
            }
#pragma unroll
            for (int r = 0; r < 4; ++r)
                ob[(size_t)(c0 + g * 4 + r) * DHW + tt * 16 + l15] = o[r];
        }
    }
}

extern "C" void kernel_launch(void* const* d_in, const int* in_sizes, int n_in,
                              void* d_out, int out_size, void* d_ws, size_t ws_size,
                              hipStream_t stream)
{
    const float* q_map  = (const float*)d_in[0];
    const float* k_map  = (const float*)d_in[1];
    const float* v_map  = (const float*)d_in[2];
    const float* lnq_w  = (const float*)d_in[3];
    const float* lnq_b  = (const float*)d_in[4];
    const float* lnkv_w = (const float*)d_in[5];
    const float* lnkv_b = (const float*)d_in[6];
    const float* proj_w = (const float*)d_in[7];
    const float* proj_b = (const float*)d_in[8];
    float* out = (float*)d_out;

    const size_t SZ = (size_t)NTOK * C_;
    _Float16* qh = (_Float16*)d_ws;
    _Float16* kh = qh + SZ;
    _Float16* vh = kh + SZ;
    _Float16* ah = vh + SZ;
    _Float16* wh = ah + SZ;

    k_convert_w<<<64, 256, 0, stream>>>(proj_w, wh);
    k_ln<<<dim3(6912, 3), 256, 0, stream>>>(q_map, k_map, v_map,
                                            lnq_w, lnq_b, lnkv_w, lnkv_b, qh, kh, vh);
    k_attn<<<8192, 256, 0, stream>>>(qh, kh, vh, ah);
    k_proj<<<3456, 256, 0, stream>>>(ah, wh, proj_b, out);
}

// Round 4
// 509.200 us; speedup vs baseline: 2.5158x; 1.2799x over previous
//
#include <hip/hip_runtime.h>

#define C_    256
#define DHW   110592
#define NTOK  221184   // B * DHW
#define NSEQ  216      // tokens per window
#define NH    8
#define DH    32

typedef _Float16 half8  __attribute__((ext_vector_type(8)));
typedef _Float16 half4v __attribute__((ext_vector_type(4)));
typedef __fp16   fp16x2 __attribute__((ext_vector_type(2)));
typedef float    float4v  __attribute__((ext_vector_type(4)));
typedef float    float16v __attribute__((ext_vector_type(16)));

union H8U4 { half8 h; uint4 u; };
union H2U1 { fp16x2 h; unsigned u; };

static __device__ __forceinline__ unsigned pkrtz(float a, float b) {
    H2U1 t; t.h = __builtin_amdgcn_cvt_pkrtz(a, b); return t.u;
}

// ---------------- Kernel 0: convert proj_w fp32 -> fp16 ----------------
__global__ __launch_bounds__(256) void k_convert_w(const float* __restrict__ w,
                                                   _Float16* __restrict__ wh) {
    int i = blockIdx.x * 256 + threadIdx.x;
#pragma unroll
    for (int j = 0; j < 4; ++j) {
        int idx = i + j * 16384;
        wh[idx] = (_Float16)w[idx];
    }
}

// ---------------- Kernel 1: window-partition + LayerNorm, single-pass ----------------
// For m==0 (q), fold attention scale * log2(e) into LN weight+bias so k_attn's
// QK^T output feeds exp2 directly.
__global__ __launch_bounds__(256) void k_ln(
    const float* __restrict__ q_map, const float* __restrict__ k_map,
    const float* __restrict__ v_map,
    const float* __restrict__ lnq_w, const float* __restrict__ lnq_b,
    const float* __restrict__ lnkv_w, const float* __restrict__ lnkv_b,
    _Float16* __restrict__ qo, _Float16* __restrict__ ko, _Float16* __restrict__ vo)
{
    __shared__ float ps1[8][32];
    __shared__ float ps2[8][32];
    const int tid = threadIdx.x;
    const int g = tid >> 5, t = tid & 31;
    const int m = blockIdx.y;
    const float* xm = (m == 0) ? q_map : (m == 1) ? k_map : v_map;
    _Float16*   xo = (m == 0) ? qo    : (m == 1) ? ko    : vo;
    const float* wv = (m == 0) ? lnq_w : lnkv_w;
    const float* bv = (m == 0) ? lnq_b : lnkv_b;
    const float sc = (m == 0) ? (0.17677669529663687f * 1.4426950408889634f) : 1.0f;

    const int blk = blockIdx.x;
    const int b = blk / 3456;
    const int pos = (blk - b * 3456) * 32 + t;

    const int d = pos / 2304, rem = pos % 2304, h = rem / 48, w = rem % 48;
    const int wi = (d / 6) * 64 + (h / 6) * 8 + (w / 6);
    const int n = (d % 6) * 36 + (h % 6) * 6 + (w % 6);
    const long outRow = (long)(b * 512 + wi) * NSEQ + n;

    const float* xp = xm + (size_t)b * C_ * DHW + pos;
    float x[32];
    float s1 = 0.f, s2 = 0.f;
#pragma unroll
    for (int i = 0; i < 32; ++i) {
        x[i] = xp[(size_t)(g * 32 + i) * DHW];
        s1 += x[i]; s2 += x[i] * x[i];
    }
    ps1[g][t] = s1; ps2[g][t] = s2;
    __syncthreads();
    float a1 = 0.f, a2 = 0.f;
#pragma unroll
    for (int gg = 0; gg < 8; ++gg) { a1 += ps1[gg][t]; a2 += ps2[gg][t]; }
    float mu = a1 * (1.f / 256.f);
    float rstd = rsqrtf(a2 * (1.f / 256.f) - mu * mu + 1e-5f);

    _Float16* op = xo + (size_t)outRow * C_ + g * 32;
#pragma unroll
    for (int i0 = 0; i0 < 32; i0 += 8) {
        half8 y;
#pragma unroll
        for (int i = 0; i < 8; ++i) {
            int c = g * 32 + i0 + i;
            y[i] = (_Float16)(((x[i0 + i] - mu) * rstd * wv[c] + bv[c]) * sc);
        }
        *(half8*)(op + i0) = y;
    }
}

// ---------------- Kernel 2: per-(window, head) attention, 32x32 MFMA ----------------
// 7 waves; wave w owns q-rows [w*32, w*32+32). S^T = K*Q^T (col=q lane-local) ->
// per-lane exp2/sum -> pkrtz + permlane32_swap remap -> PV, all in registers.
__global__ __launch_bounds__(448) void k_attn(
    const _Float16* __restrict__ qh, const _Float16* __restrict__ kh,
    const _Float16* __restrict__ vh, _Float16* __restrict__ ao)
{
    __shared__ _Float16 Ks[224 * 32];   // [k][d], 16B cols swizzled by ((k>>1)&3)
    __shared__ _Float16 Vb[28 * 256];   // [kblk][d][8] : V[kblk*8+j][d] at kblk*256+d*8+j
    __shared__ float rsum[7 * 32];

    const int tid = threadIdx.x;
    const int wave = tid >> 6, lane = tid & 63;
    const int l31 = lane & 31, h = lane >> 5;
    const int win = blockIdx.x >> 3, head = blockIdx.x & 7;
    const size_t base = ((size_t)win * NSEQ) * C_ + head * DH;

    // ---- stage K: vector loads, swizzled 16B-column writes (conflict-free) ----
#pragma unroll
    for (int it = 0; it < 2; ++it) {
        int idx = tid + it * 448;        // 0..895
        int r = idx >> 2, c8 = idx & 3;
        half8 kv{};
        if (r < NSEQ) kv = *(const half8*)(kh + base + (size_t)r * C_ + c8 * 8);
        *(half8*)(&Ks[r * 32 + ((c8 ^ ((r >> 1) & 3)) * 8)]) = kv;
    }
    // ---- stage V transposed-gather: 2B global loads (64B segments), b128 LDS writes ----
#pragma unroll
    for (int it = 0; it < 2; ++it) {
        int idx = tid + it * 448;        // 0..895 -> (kblk, d)
        int kb = idx >> 5, d = idx & 31; // kb 0..27
        const _Float16* vp = vh + base + (size_t)(kb * 8) * C_ + d;
        half8 vv{};
#pragma unroll
        for (int j = 0; j < 8; ++j) {
            int r = kb * 8 + j;
            vv[j] = (r < NSEQ) ? vp[(size_t)j * C_] : (_Float16)0;
        }
        *(half8*)(&Vb[kb * 256 + d * 8]) = vv;
    }

    // ---- Q fragments (B operand): rows wave*32 + l31, d-chunks 8h and 16+8h ----
    const int qrow = wave * 32 + l31;
    half8 qf0{}, qf1{};
    if (qrow < NSEQ) {
        const _Float16* qp = qh + base + (size_t)qrow * C_ + h * 8;
        qf0 = *(const half8*)(qp);
        qf1 = *(const half8*)(qp + 16);
    }
    __syncthreads();

    float16v O{};
    float sum = 0.f;

#pragma unroll
    for (int kt = 0; kt < 7; ++kt) {
        const int krow = kt * 32 + l31;
        const int sw = (krow >> 1) & 3;
        half8 kf0 = *(const half8*)(&Ks[krow * 32 + ((h ^ sw) * 8)]);
        half8 kf1 = *(const half8*)(&Ks[krow * 32 + (((2 + h) ^ sw) * 8)]);
        float16v s{};
        s = __builtin_amdgcn_mfma_f32_32x32x16_f16(kf0, qf0, s, 0, 0, 0);
        s = __builtin_amdgcn_mfma_f32_32x32x16_f16(kf1, qf1, s, 0, 0, 0);

        // exp2 (scale already folded into q); regs r>=12 of kt==6 are k-pads (216..223)
        const int RV = (kt == 6) ? 12 : 16;
        float p[16];
#pragma unroll
        for (int r = 0; r < 16; ++r) p[r] = (r < RV) ? exp2f(s[r]) : 0.f;
#pragma unroll
        for (int r = 0; r < 16; ++r) sum += p[r];

        // PV: two 16-k chunks; A-frag built via pkrtz + permlane32_swap
#pragma unroll
        for (int m = 0; m < 2; ++m) {
            const int rb = m * 8;
            unsigned a0 = pkrtz(p[rb + 0], p[rb + 1]);
            unsigned a1 = pkrtz(p[rb + 2], p[rb + 3]);
            unsigned a2 = pkrtz(p[rb + 4], p[rb + 5]);
            unsigned a3 = pkrtz(p[rb + 6], p[rb + 7]);
            asm volatile("v_permlane32_swap_b32 %0, %1" : "+v"(a0), "+v"(a2));
            asm volatile("v_permlane32_swap_b32 %0, %1" : "+v"(a1), "+v"(a3));
            H8U4 pa;
            pa.u.x = a0; pa.u.y = a1; pa.u.z = a2; pa.u.w = a3;
            half8 vb = *(const half8*)(&Vb[(kt * 4 + m * 2 + h) * 256 + l31 * 8]);
            O = __builtin_amdgcn_mfma_f32_32x32x16_f16(pa.h, vb, O, 0, 0, 0);
        }
    }

    // ---- normalize + store ----
    float tot = sum + __shfl_xor(sum, 32);
    if (h == 0) rsum[wave * 32 + l31] = 1.f / tot;
    __syncthreads();

    float4 r0 = *(const float4*)(&rsum[wave * 32 + 4 * h + 0]);
    float4 r1 = *(const float4*)(&rsum[wave * 32 + 4 * h + 8]);
    float4 r2 = *(const float4*)(&rsum[wave * 32 + 4 * h + 16]);
    float4 r3 = *(const float4*)(&rsum[wave * 32 + 4 * h + 24]);
    float rv[16] = {r0.x, r0.y, r0.z, r0.w, r1.x, r1.y, r1.z, r1.w,
                    r2.x, r2.y, r2.z, r2.w, r3.x, r3.y, r3.z, r3.w};

    _Float16* aop = ao + ((size_t)win * NSEQ + wave * 32) * C_ + head * DH + l31;
#pragma unroll
    for (int r = 0; r < 16; ++r) {
        int qp = (r & 3) + 8 * (r >> 2) + 4 * h;
        if (wave * 32 + qp < NSEQ)
            aop[(size_t)qp * C_] = (_Float16)(O[r] * rv[r]);
    }
}

// ---------------- Kernel 3: projection GEMM + bias + window reverse ----------------
__global__ __launch_bounds__(256) void k_proj(
    const _Float16* __restrict__ ah, const _Float16* __restrict__ wh,
    const float* __restrict__ pb, float* __restrict__ out)
{
    __shared__ _Float16 As[64 * 264];
    const int tid = threadIdx.x;
    const int wave = tid >> 6, lane = tid & 63;
    const int l15 = lane & 15, g = lane >> 4;
    const long tok0 = (long)blockIdx.x * 64;

    {
        int r = tid >> 2, c8 = tid & 3;
        long tok = tok0 + r;
        int b = (int)(tok / DHW);
        int pos = (int)(tok - (long)b * DHW);
        int d = pos / 2304, rem = pos % 2304, hh = rem / 48, ww = rem % 48;
        int wi = (d / 6) * 64 + (hh / 6) * 8 + (ww / 6);
        int n = (d % 6) * 36 + (hh % 6) * 6 + (ww % 6);
        const _Float16* src = ah + ((size_t)(b * 512 + wi) * NSEQ + n) * C_;
        _Float16* dst = &As[r * 264];
#pragma unroll
        for (int i = 0; i < 8; ++i)
            *(half8*)(dst + c8 * 8 + i * 32) = *(const half8*)(src + c8 * 8 + i * 32);
    }
    __syncthreads();

    const int b0 = (int)(tok0 / DHW);
    const int pos0 = (int)(tok0 - (long)b0 * DHW);
    float* ob = out + (size_t)b0 * C_ * DHW + pos0;

#pragma unroll
    for (int ct = 0; ct < 4; ++ct) {
        const int c0 = wave * 64 + ct * 16;
        half8 afr[8];
#pragma unroll
        for (int kc = 0; kc < 8; ++kc)
            afr[kc] = *(const half8*)(wh + (size_t)(c0 + l15) * C_ + kc * 32 + g * 8);
        float4 bq = *(const float4*)(pb + c0 + g * 4);
#pragma unroll
        for (int tt = 0; tt < 4; ++tt) {
            float4v o = {bq.x, bq.y, bq.z, bq.w};
#pragma unroll
            for (int kc = 0; kc < 8; ++kc) {
                half8 bfr = *(const half8*)(&As[(tt * 16 + l15) * 264 + kc * 32 + g * 8]);
                o = __builtin_amdgcn_mfma_f32_16x16x32_f16(afr[kc], bfr, o, 0, 0, 0);
            }
#pragma unroll
            for (int r = 0; r < 4; ++r)
                ob[(size_t)(c0 + g * 4 + r) * DHW + tt * 16 + l15] = o[r];
        }
    }
}

extern "C" void kernel_launch(void* const* d_in, const int* in_sizes, int n_in,
                              void* d_out, int out_size, void* d_ws, size_t ws_size,
                              hipStream_t stream)
{
    const float* q_map  = (const float*)d_in[0];
    const float* k_map  = (const float*)d_in[1];
    const float* v_map  = (const float*)d_in[2];
    const float* lnq_w  = (const float*)d_in[3];
    const float* lnq_b  = (const float*)d_in[4];
    const float* lnkv_w = (const float*)d_in[5];
    const float* lnkv_b = (const float*)d_in[6];
    const float* proj_w = (const float*)d_in[7];
    const float* proj_b = (const float*)d_in[8];
    float* out = (float*)d_out;

    const size_t SZ = (size_t)NTOK * C_;
    _Float16* qh = (_Float16*)d_ws;
    _Float16* kh = qh + SZ;
    _Float16* vh = kh + SZ;
    _Float16* ah = vh + SZ;
    _Float16* wh = ah + SZ;

    k_convert_w<<<64, 256, 0, stream>>>(proj_w, wh);
    k_ln<<<dim3(6912, 3), 256, 0, stream>>>(q_map, k_map, v_map,
                                            lnq_w, lnq_b, lnkv_w, lnkv_b, qh, kh, vh);
    k_attn<<<8192, 448, 0, stream>>>(qh, kh, vh, ah);
    k_proj<<<3456, 256, 0, stream>>>(ah, wh, proj_b, out);
}

// Round 5
// 457.653 us; speedup vs baseline: 2.7992x; 1.1126x over previous
//
#include <hip/hip_runtime.h>

#define C_    256
#define DHW   110592
#define NTOK  221184   // B * DHW
#define NSEQ  216      // tokens per window
#define NH    8
#define DH    32

typedef _Float16 half8  __attribute__((ext_vector_type(8)));
typedef _Float16 half4v __attribute__((ext_vector_type(4)));
typedef __fp16   fp16x2 __attribute__((ext_vector_type(2)));
typedef float    float4v  __attribute__((ext_vector_type(4)));
typedef float    float16v __attribute__((ext_vector_type(16)));

union H8U4 { half8 h; uint4 u; };
union H2U1 { fp16x2 h; unsigned u; };

static __device__ __forceinline__ unsigned pkrtz(float a, float b) {
    H2U1 t; t.h = __builtin_amdgcn_cvt_pkrtz(a, b); return t.u;
}

// ---------------- Kernel 0: convert proj_w fp32 -> fp16 ----------------
__global__ __launch_bounds__(256) void k_convert_w(const float* __restrict__ w,
                                                   _Float16* __restrict__ wh) {
    int i = blockIdx.x * 256 + threadIdx.x;
#pragma unroll
    for (int j = 0; j < 4; ++j) {
        int idx = i + j * 16384;
        wh[idx] = (_Float16)w[idx];
    }
}

// ---------------- Kernel 1: window-partition + LayerNorm, vectorized ----------------
// Block: 64 consecutive flat tokens of one matrix (grid.y = q/k/v).
// Thread (tx=tid&15, cg=tid>>4): 16 float4 loads = 4 tokens x 16 channels.
// For m==0 (q), fold attention scale*log2(e) into the output.
__global__ __launch_bounds__(256) void k_ln(
    const float* __restrict__ q_map, const float* __restrict__ k_map,
    const float* __restrict__ v_map,
    const float* __restrict__ lnq_w, const float* __restrict__ lnq_b,
    const float* __restrict__ lnkv_w, const float* __restrict__ lnkv_b,
    _Float16* __restrict__ qo, _Float16* __restrict__ ko, _Float16* __restrict__ vo)
{
    __shared__ float ps1[64][20];
    __shared__ float ps2[64][20];
    const int tid = threadIdx.x;
    const int tx = tid & 15;    // token quad id
    const int cg = tid >> 4;    // channel group (16 channels)
    const int m = blockIdx.y;
    const float* xm = (m == 0) ? q_map : (m == 1) ? k_map : v_map;
    _Float16*   xo = (m == 0) ? qo    : (m == 1) ? ko    : vo;
    const float* wv = (m == 0) ? lnq_w : lnkv_w;
    const float* bv = (m == 0) ? lnq_b : lnkv_b;
    const float sc = (m == 0) ? (0.17677669529663687f * 1.4426950408889634f) : 1.0f;

    const long pg = (long)blockIdx.x * 64;
    const int b = (int)(pg / DHW);
    const int pos = (int)(pg - (long)b * DHW);

    const float* xp = xm + (size_t)b * C_ * DHW + pos + tx * 4;
    float4 x[16];
    float s1[4] = {0.f, 0.f, 0.f, 0.f};
    float s2[4] = {0.f, 0.f, 0.f, 0.f};
#pragma unroll
    for (int i = 0; i < 16; ++i) {
        x[i] = *(const float4*)(xp + (size_t)(cg * 16 + i) * DHW);
        s1[0] += x[i].x; s2[0] += x[i].x * x[i].x;
        s1[1] += x[i].y; s2[1] += x[i].y * x[i].y;
        s1[2] += x[i].z; s2[2] += x[i].z * x[i].z;
        s1[3] += x[i].w; s2[3] += x[i].w * x[i].w;
    }
#pragma unroll
    for (int j = 0; j < 4; ++j) { ps1[tx * 4 + j][cg] = s1[j]; ps2[tx * 4 + j][cg] = s2[j]; }
    __syncthreads();

    float mu[4], rs[4];
#pragma unroll
    for (int j = 0; j < 4; ++j) {
        float a1 = 0.f, a2 = 0.f;
#pragma unroll
        for (int cc = 0; cc < 4; ++cc) {
            float4 p1 = *(const float4*)(&ps1[tx * 4 + j][cc * 4]);
            float4 p2 = *(const float4*)(&ps2[tx * 4 + j][cc * 4]);
            a1 += (p1.x + p1.y) + (p1.z + p1.w);
            a2 += (p2.x + p2.y) + (p2.z + p2.w);
        }
        mu[j] = a1 * (1.f / 256.f);
        rs[j] = rsqrtf(a2 * (1.f / 256.f) - mu[j] * mu[j] + 1e-5f);
    }

    float wr[16], br[16];
#pragma unroll
    for (int cc = 0; cc < 4; ++cc) {
        float4 wq = *(const float4*)(wv + cg * 16 + cc * 4);
        float4 bq = *(const float4*)(bv + cg * 16 + cc * 4);
        wr[cc * 4 + 0] = wq.x * sc; br[cc * 4 + 0] = bq.x * sc;
        wr[cc * 4 + 1] = wq.y * sc; br[cc * 4 + 1] = bq.y * sc;
        wr[cc * 4 + 2] = wq.z * sc; br[cc * 4 + 2] = bq.z * sc;
        wr[cc * 4 + 3] = wq.w * sc; br[cc * 4 + 3] = bq.w * sc;
    }

#pragma unroll
    for (int j = 0; j < 4; ++j) {
        const int p = pos + tx * 4 + j;
        const int d = p / 2304, rem = p % 2304, hh = rem / 48, ww = rem % 48;
        const int wi = (d / 6) * 64 + (hh / 6) * 8 + (ww / 6);
        const int n = (d % 6) * 36 + (hh % 6) * 6 + (ww % 6);
        _Float16* op = xo + ((size_t)(b * 512 + wi) * NSEQ + n) * C_ + cg * 16;
        half8 y0, y1;
#pragma unroll
        for (int i = 0; i < 8; ++i) {
            float xa = (j == 0) ? x[i].x : (j == 1) ? x[i].y : (j == 2) ? x[i].z : x[i].w;
            float xb = (j == 0) ? x[i + 8].x : (j == 1) ? x[i + 8].y : (j == 2) ? x[i + 8].z : x[i + 8].w;
            y0[i] = (_Float16)((xa - mu[j]) * rs[j] * wr[i] + br[i]);
            y1[i] = (_Float16)((xb - mu[j]) * rs[j] * wr[i + 8] + br[i + 8]);
        }
        *(half8*)op = y0;
        *(half8*)(op + 8) = y1;
    }
}

// ---------------- Kernel 2: per-(window, head) attention, 32x32 MFMA ----------------
// XCD-chunked swizzle: all 8 heads of a window on one XCD (L2 K/V reuse).
__global__ __launch_bounds__(448) void k_attn(
    const _Float16* __restrict__ qh, const _Float16* __restrict__ kh,
    const _Float16* __restrict__ vh, _Float16* __restrict__ ao)
{
    __shared__ _Float16 Ks[224 * 32];   // [k][d], 16B cols swizzled by ((k>>1)&3)
    __shared__ _Float16 Vb[28 * 256];   // [kblk][d][8]
    __shared__ float rsum[7 * 32];

    const int tid = threadIdx.x;
    const int wave = tid >> 6, lane = tid & 63;
    const int l31 = lane & 31, h = lane >> 5;
    const int o = ((blockIdx.x & 7) << 10) | (blockIdx.x >> 3);
    const int win = o >> 3, head = o & 7;
    const size_t base = ((size_t)win * NSEQ) * C_ + head * DH;

    // ---- stage K ----
#pragma unroll
    for (int it = 0; it < 2; ++it) {
        int idx = tid + it * 448;
        int r = idx >> 2, c8 = idx & 3;
        half8 kv{};
        if (r < NSEQ) kv = *(const half8*)(kh + base + (size_t)r * C_ + c8 * 8);
        *(half8*)(&Ks[r * 32 + ((c8 ^ ((r >> 1) & 3)) * 8)]) = kv;
    }
    // ---- stage V transposed-gather ----
#pragma unroll
    for (int it = 0; it < 2; ++it) {
        int idx = tid + it * 448;
        int kb = idx >> 5, d = idx & 31;
        const _Float16* vp = vh + base + (size_t)(kb * 8) * C_ + d;
        half8 vv{};
#pragma unroll
        for (int j = 0; j < 8; ++j) {
            int r = kb * 8 + j;
            vv[j] = (r < NSEQ) ? vp[(size_t)j * C_] : (_Float16)0;
        }
        *(half8*)(&Vb[kb * 256 + d * 8]) = vv;
    }

    const int qrow = wave * 32 + l31;
    half8 qf0{}, qf1{};
    if (qrow < NSEQ) {
        const _Float16* qp = qh + base + (size_t)qrow * C_ + h * 8;
        qf0 = *(const half8*)(qp);
        qf1 = *(const half8*)(qp + 16);
    }
    __syncthreads();

    float16v O{};
    float sum = 0.f;

#pragma unroll
    for (int kt = 0; kt < 7; ++kt) {
        const int krow = kt * 32 + l31;
        const int sw = (krow >> 1) & 3;
        half8 kf0 = *(const half8*)(&Ks[krow * 32 + ((h ^ sw) * 8)]);
        half8 kf1 = *(const half8*)(&Ks[krow * 32 + (((2 + h) ^ sw) * 8)]);
        float16v s{};
        s = __builtin_amdgcn_mfma_f32_32x32x16_f16(kf0, qf0, s, 0, 0, 0);
        s = __builtin_amdgcn_mfma_f32_32x32x16_f16(kf1, qf1, s, 0, 0, 0);

        const int RV = (kt == 6) ? 12 : 16;
        float p[16];
#pragma unroll
        for (int r = 0; r < 16; ++r) p[r] = (r < RV) ? exp2f(s[r]) : 0.f;
#pragma unroll
        for (int r = 0; r < 16; ++r) sum += p[r];

#pragma unroll
        for (int m = 0; m < 2; ++m) {
            const int rb = m * 8;
            unsigned a0 = pkrtz(p[rb + 0], p[rb + 1]);
            unsigned a1 = pkrtz(p[rb + 2], p[rb + 3]);
            unsigned a2 = pkrtz(p[rb + 4], p[rb + 5]);
            unsigned a3 = pkrtz(p[rb + 6], p[rb + 7]);
            asm volatile("v_permlane32_swap_b32 %0, %1" : "+v"(a0), "+v"(a2));
            asm volatile("v_permlane32_swap_b32 %0, %1" : "+v"(a1), "+v"(a3));
            H8U4 pa;
            pa.u.x = a0; pa.u.y = a1; pa.u.z = a2; pa.u.w = a3;
            half8 vb = *(const half8*)(&Vb[(kt * 4 + m * 2 + h) * 256 + l31 * 8]);
            O = __builtin_amdgcn_mfma_f32_32x32x16_f16(pa.h, vb, O, 0, 0, 0);
        }
    }

    float tot = sum + __shfl_xor(sum, 32);
    if (h == 0) rsum[wave * 32 + l31] = 1.f / tot;
    __syncthreads();

    float4 r0 = *(const float4*)(&rsum[wave * 32 + 4 * h + 0]);
    float4 r1 = *(const float4*)(&rsum[wave * 32 + 4 * h + 8]);
    float4 r2 = *(const float4*)(&rsum[wave * 32 + 4 * h + 16]);
    float4 r3 = *(const float4*)(&rsum[wave * 32 + 4 * h + 24]);
    float rv[16] = {r0.x, r0.y, r0.z, r0.w, r1.x, r1.y, r1.z, r1.w,
                    r2.x, r2.y, r2.z, r2.w, r3.x, r3.y, r3.z, r3.w};

    _Float16* aop = ao + ((size_t)win * NSEQ + wave * 32) * C_ + head * DH + l31;
#pragma unroll
    for (int r = 0; r < 16; ++r) {
        int qp = (r & 3) + 8 * (r >> 2) + 4 * h;
        if (wave * 32 + qp < NSEQ)
            aop[(size_t)qp * C_] = (_Float16)(O[r] * rv[r]);
    }
}

// ---------------- Kernel 3: projection GEMM + bias + window reverse ----------------
__global__ __launch_bounds__(256) void k_proj(
    const _Float16* __restrict__ ah, const _Float16* __restrict__ wh,
    const float* __restrict__ pb, float* __restrict__ out)
{
    __shared__ _Float16 As[64 * 264];
    const int tid = threadIdx.x;
    const int wave = tid >> 6, lane = tid & 63;
    const int l15 = lane & 15, g = lane >> 4;
    const long tok0 = (long)blockIdx.x * 64;

    {
        int r = tid >> 2, c8 = tid & 3;
        long tok = tok0 + r;
        int b = (int)(tok / DHW);
        int pos = (int)(tok - (long)b * DHW);
        int d = pos / 2304, rem = pos % 2304, hh = rem / 48, ww = rem % 48;
        int wi = (d / 6) * 64 + (hh / 6) * 8 + (ww / 6);
        int n = (d % 6) * 36 + (hh % 6) * 6 + (ww % 6);
        const _Float16* src = ah + ((size_t)(b * 512 + wi) * NSEQ + n) * C_;
        _Float16* dst = &As[r * 264];
#pragma unroll
        for (int i = 0; i < 8; ++i)
            *(half8*)(dst + c8 * 8 + i * 32) = *(const half8*)(src + c8 * 8 + i * 32);
    }
    __syncthreads();

    const int b0 = (int)(tok0 / DHW);
    const int pos0 = (int)(tok0 - (long)b0 * DHW);
    float* ob = out + (size_t)b0 * C_ * DHW + pos0;

#pragma unroll
    for (int ct = 0; ct < 4; ++ct) {
        const int c0 = wave * 64 + ct * 16;
        half8 afr[8];
#pragma unroll
        for (int kc = 0; kc < 8; ++kc)
            afr[kc] = *(const half8*)(wh + (size_t)(c0 + l15) * C_ + kc * 32 + g * 8);
        float4 bq = *(const float4*)(pb + c0 + g * 4);
#pragma unroll
        for (int tt = 0; tt < 4; ++tt) {
            float4v o = {bq.x, bq.y, bq.z, bq.w};
#pragma unroll
            for (int kc = 0; kc < 8; ++kc) {
                half8 bfr = *(const half8*)(&As[(tt * 16 + l15) * 264 + kc * 32 + g * 8]);
                o = __builtin_amdgcn_mfma_f32_16x16x32_f16(afr[kc], bfr, o, 0, 0, 0);
            }
#pragma unroll
            for (int r = 0; r < 4; ++r)
                ob[(size_t)(c0 + g * 4 + r) * DHW + tt * 16 + l15] = o[r];
        }
    }
}

extern "C" void kernel_launch(void* const* d_in, const int* in_sizes, int n_in,
                              void* d_out, int out_size, void* d_ws, size_t ws_size,
                              hipStream_t stream)
{
    const float* q_map  = (const float*)d_in[0];
    const float* k_map  = (const float*)d_in[1];
    const float* v_map  = (const float*)d_in[2];
    const float* lnq_w  = (const float*)d_in[3];
    const float* lnq_b  = (const float*)d_in[4];
    const float* lnkv_w = (const float*)d_in[5];
    const float* lnkv_b = (const float*)d_in[6];
    const float* proj_w = (const float*)d_in[7];
    const float* proj_b = (const float*)d_in[8];
    float* out = (float*)d_out;

    const size_t SZ = (size_t)NTOK * C_;
    _Float16* qh = (_Float16*)d_ws;
    _Float16* kh = qh + SZ;
    _Float16* vh = kh + SZ;
    _Float16* ah = vh + SZ;
    _Float16* wh = ah + SZ;

    k_convert_w<<<64, 256, 0, stream>>>(proj_w, wh);
    k_ln<<<dim3(3456, 3), 256, 0, stream>>>(q_map, k_map, v_map,
                                            lnq_w, lnq_b, lnkv_w, lnkv_b, qh, kh, vh);
    k_attn<<<8192, 448, 0, stream>>>(qh, kh, vh, ah);
    k_proj<<<3456, 256, 0, stream>>>(ah, wh, proj_b, out);
}